// Round 5
// baseline (247.762 us; speedup 1.0000x reference)
//
#include <hip/hip_runtime.h>

#define BB 64
#define TT 512
#define HH 768
#define KK 11
#define START_ID 9
#define NEGV -10000.0f

typedef float vf2 __attribute__((ext_vector_type(2)));

__device__ __forceinline__ float rlane(float v, int l) {
    return __int_as_float(__builtin_amdgcn_readlane(__float_as_int(v), l));
}

// DPP wave-64 sum reduction -> lane 63 (VALU path, no LDS)
template <int CTRL>
__device__ __forceinline__ float dpp_add(float x) {
    int yi = __builtin_amdgcn_update_dpp(0, __float_as_int(x), CTRL, 0xF, 0xF, false);
    return x + __int_as_float(yi);
}
__device__ __forceinline__ float wave_sum_to_lane63(float x) {
    x = dpp_add<0x111>(x);  // row_shr:1
    x = dpp_add<0x112>(x);  // row_shr:2
    x = dpp_add<0x114>(x);  // row_shr:4
    x = dpp_add<0x118>(x);  // row_shr:8
    x = dpp_add<0x142>(x);  // row_bcast:15
    x = dpp_add<0x143>(x);  // row_bcast:31 -> lane63 = full sum
    return x;
}

// ---------------------------------------------------------------------------
// Fully fused: one block per batch. 8 waves do the batch's FC straight into
// LDS (no global feats, no second launch, no cross-block sync), then the
// bit-exact Viterbi phases run on the same LDS.
// ---------------------------------------------------------------------------
__global__ __launch_bounds__(512, 2) void crf_fused(const float* __restrict__ embeds,
                                                    const float* __restrict__ W,
                                                    const float* __restrict__ bias,
                                                    const float* __restrict__ trans,
                                                    float* __restrict__ out) {
    __shared__ __align__(16) float feats_lds[(TT + 4) * KK];  // +4 pad rows for phase-1 ring
    __shared__ __align__(16) float dh[(TT - 1) * 12];         // delta history, stride 12
    __shared__ int psi_lds[(TT - 1) * KK];
    __shared__ float tr_lds[KK * KK];
    __shared__ int comp[15 * KK];
    __shared__ int bt[16];
    __shared__ int sh_last;

    const int tid = threadIdx.x;
    const int lane = tid & 63;
    const int wv = tid >> 6;          // 0..7
    const int b = blockIdx.x;

    if (tid < KK * KK) tr_lds[tid] = trans[tid];

    // ---- FC into LDS: wave wv computes rows [64*wv, 64*wv+64) of this batch ----
    {
        float4 wf[KK][3];
#pragma unroll
        for (int k = 0; k < KK; ++k)
#pragma unroll
            for (int r = 0; r < 3; ++r)
                wf[k][r] = *reinterpret_cast<const float4*>(W + k * HH + r * 256 + lane * 4);

        float bk[KK];
#pragma unroll
        for (int k = 0; k < KK; ++k) bk[k] = bias[k];  // uniform -> SGPRs

        const float* ebase = embeds + (size_t)b * TT * HH;
#pragma unroll 1
        for (int it = 0; it < 32; ++it) {
            const int r0 = wv * 64 + it * 2;
            const float* ea = ebase + (size_t)r0 * HH;
            const float* eb = ea + HH;
            float4 a0 = *reinterpret_cast<const float4*>(ea + 0   + lane * 4);
            float4 a1 = *reinterpret_cast<const float4*>(ea + 256 + lane * 4);
            float4 a2 = *reinterpret_cast<const float4*>(ea + 512 + lane * 4);
            float4 b0 = *reinterpret_cast<const float4*>(eb + 0   + lane * 4);
            float4 b1 = *reinterpret_cast<const float4*>(eb + 256 + lane * 4);
            float4 b2 = *reinterpret_cast<const float4*>(eb + 512 + lane * 4);

            vf2 va[6] = {{a0.x, a0.y}, {a0.z, a0.w}, {a1.x, a1.y},
                         {a1.z, a1.w}, {a2.x, a2.y}, {a2.z, a2.w}};
            vf2 vb[6] = {{b0.x, b0.y}, {b0.z, b0.w}, {b1.x, b1.y},
                         {b1.z, b1.w}, {b2.x, b2.y}, {b2.z, b2.w}};

            float rA[KK], rB[KK];
#pragma unroll
            for (int k = 0; k < KK; ++k) {
                vf2 wv0 = {wf[k][0].x, wf[k][0].y}, wv1 = {wf[k][0].z, wf[k][0].w};
                vf2 wv2 = {wf[k][1].x, wf[k][1].y}, wv3 = {wf[k][1].z, wf[k][1].w};
                vf2 wv4 = {wf[k][2].x, wf[k][2].y}, wv5 = {wf[k][2].z, wf[k][2].w};
                vf2 sA = va[0] * wv0;
                vf2 sB = vb[0] * wv0;
                sA += va[1] * wv1;  sB += vb[1] * wv1;
                sA += va[2] * wv2;  sB += vb[2] * wv2;
                sA += va[3] * wv3;  sB += vb[3] * wv3;
                sA += va[4] * wv4;  sB += vb[4] * wv4;
                sA += va[5] * wv5;  sB += vb[5] * wv5;
                rA[k] = wave_sum_to_lane63(sA.x + sA.y);
                rB[k] = wave_sum_to_lane63(sB.x + sB.y);
            }
            if (lane == 63) {
#pragma unroll
                for (int k = 0; k < KK; ++k) feats_lds[r0 * KK + k] = rA[k] + bk[k];
#pragma unroll
                for (int k = 0; k < KK; ++k) feats_lds[(r0 + 1) * KK + k] = rB[k] + bk[k];
            }
        }
    }
    __syncthreads();

    // ---- Phase 1: forward recurrence (wave 0 only) ----
    if (tid < 64) {
        const int i = tid;
        const int ci = (i < KK) ? i : 0;
        float tr[KK];
#pragma unroll
        for (int j = 0; j < KK; ++j) tr[j] = (i < KK) ? tr_lds[i * KK + j] : NEGV;

        float delta = (i == START_ID) ? 0.0f : NEGV;

        auto vstep = [&](int t, float fcur) {
            if (i < KK) dh[(t - 1) * 12 + i] = delta;   // pre-step delta (off-chain)
            float dj[KK];
#pragma unroll
            for (int j = 0; j < KK; ++j) dj[j] = rlane(delta, j);
            float s[KK];
#pragma unroll
            for (int j = 0; j < KK; ++j) s[j] = tr[j] + dj[j];
            float t0 = fmaxf(fmaxf(s[0], s[1]), s[2]);
            float t1 = fmaxf(fmaxf(s[3], s[4]), s[5]);
            float t2 = fmaxf(fmaxf(s[6], s[7]), s[8]);
            float t3 = fmaxf(s[9], s[10]);
            float best = fmaxf(fmaxf(fmaxf(t0, t1), t2), t3);
            delta = best + fcur;
        };

        float fr0 = feats_lds[1 * KK + ci];
        float fr1 = feats_lds[2 * KK + ci];
        float fr2 = feats_lds[3 * KK + ci];
        float fr3 = feats_lds[4 * KK + ci];

        int t = 1;
#pragma unroll 1
        for (; t <= TT - 4; t += 4) {
            vstep(t,     fr0); fr0 = feats_lds[(t + 4) * KK + ci];
            vstep(t + 1, fr1); fr1 = feats_lds[(t + 5) * KK + ci];
            vstep(t + 2, fr2); fr2 = feats_lds[(t + 6) * KK + ci];
            vstep(t + 3, fr3); fr3 = feats_lds[(t + 7) * KK + ci];
        }
        vstep(TT - 3, fr0);
        vstep(TT - 2, fr1);
        vstep(TT - 1, fr2);

        // score + last tag (strict-first argmax, exact)
        float dfin[KK];
#pragma unroll
        for (int j = 0; j < KK; ++j) dfin[j] = rlane(delta, j);
        float best = dfin[0];
        int last = 0;
#pragma unroll
        for (int j = 1; j < KK; ++j) {
            bool c = dfin[j] > best;
            best = c ? dfin[j] : best;
            last = c ? j : last;
        }
        if (tid == 0) {
            out[b] = best;
            out[BB + (size_t)b * TT + (TT - 1)] = (float)last;
            sh_last = last;
        }
    }
    __syncthreads();

    // ---- Phase 2: psi recompute (bit-exact), parallel over (s, i) ----
    {
        const int i = tid & 15;
        const int sg = tid >> 4;        // 0..31
        if (i < KK) {
            float tri[KK];
#pragma unroll
            for (int j = 0; j < KK; ++j) tri[j] = tr_lds[i * KK + j];
            for (int s = sg; s < TT - 1; s += 32) {
                const float4* dr = reinterpret_cast<const float4*>(dh + s * 12);
                float4 a = dr[0], c4 = dr[1], d4 = dr[2];
                float sc[KK] = {tri[0] + a.x,  tri[1] + a.y,  tri[2] + a.z,  tri[3] + a.w,
                                tri[4] + c4.x, tri[5] + c4.y, tri[6] + c4.z, tri[7] + c4.w,
                                tri[8] + d4.x, tri[9] + d4.y, tri[10] + d4.z};
                float bv = sc[0];
                int bj = 0;
#pragma unroll
                for (int j = 1; j < KK; ++j) {
                    bool c = sc[j] > bv;        // strict: first max wins
                    bv = c ? sc[j] : bv;
                    bj = c ? j : bj;
                }
                psi_lds[s * KK + i] = bj;
            }
        }
    }
    __syncthreads();

    // ---- Phase 3a: chunk composition walks (0..14) + chunk 15 real walk ----
    {
        const int c = tid >> 4;
        const int i = tid & 15;
        if (c < 15 && i < KK) {
            int cur = i;
            for (int s = c * 32 + 31; s >= c * 32; --s) cur = psi_lds[s * KK + cur];
            comp[c * KK + i] = cur;            // path[32c] given path[32(c+1)] = i
        } else if (c == 15 && i == 0) {
            int cur = sh_last;
            float* po = out + BB + (size_t)b * TT;
            for (int s = TT - 2; s >= 480; --s) {
                cur = psi_lds[s * KK + cur];
                po[s] = (float)cur;
            }
            bt[15] = cur;                      // = path[480]
        }
    }
    __syncthreads();

    // ---- Phase 3b: boundary chain ----
    if (tid == 0) {
        for (int c = 14; c >= 1; --c) bt[c] = comp[c * KK + bt[c + 1]];
    }
    __syncthreads();

    // ---- Phase 3c: parallel re-walks, store path ----
    if (tid < 15) {
        const int c = tid;
        int cur = bt[c + 1];                   // path[32(c+1)]
        float* po = out + BB + (size_t)b * TT;
        for (int s = c * 32 + 31; s >= c * 32; --s) {
            cur = psi_lds[s * KK + cur];
            po[s] = (float)cur;
        }
    }
}

extern "C" void kernel_launch(void* const* d_in, const int* in_sizes, int n_in,
                              void* d_out, int out_size, void* d_ws, size_t ws_size,
                              hipStream_t stream) {
    const float* embeds = (const float*)d_in[0];  // [B,T,H]
    const float* W_fc   = (const float*)d_in[1];  // [K,H]
    const float* b_fc   = (const float*)d_in[2];  // [K]
    const float* trans  = (const float*)d_in[3];  // [K,K]
    float* out = (float*)d_out;                   // [B] score ++ [B,T] path (as float)

    crf_fused<<<BB, 512, 0, stream>>>(embeds, W_fc, b_fc, trans, out);
}